// Round 10
// baseline (481.457 us; speedup 1.0000x reference)
//
#include <hip/hip_runtime.h>
#include <cstdint>

#define CO   64
#define CI   32
#define HH   56
#define WW   56
#define LL   3136        // 56*56
#define KK   288         // 32*9
#define KH   144         // KK/2 — double-pumped LDS tile
#define NOUT 200704u     // 64*3136
#define KG   4           // k-groups per output element in fi2
#define KCH  72          // 288 / KG
#define TO   32          // outi-tile per block in fused fi1+cumsum

// flip threshold: u < 0.008f  <=>  (ub>>9) <= 67108  <=>  ub < 67109*512
#define FLIP_LT 34359808u

// workspace layout: [0..63] atomic-max slots | 64.. wq (73728 B) | 81920.. c_ws
#define CWS_OFF_FLOATS 20480u                 // 81920 / 4
#define WS_NEED (81920ull + 4ull * 288ull * 200704ull)

__host__ __device__ inline uint32_t rotl32(uint32_t v, uint32_t r) {
#ifdef __HIP_DEVICE_COMPILE__
  return __builtin_amdgcn_alignbit(v, v, 32u - r);   // (v:v)>>(32-r) = rotl(v,r)
#else
  return (v << r) | (v >> (32u - r));
#endif
}

// shift-based rotl: on wave-uniform inputs this lowers to SALU (s_lshl/s_lshr/s_or)
__host__ __device__ inline uint32_t rotl32s(uint32_t v, uint32_t r) {
  return (v << r) | (v >> (32u - r));
}

// ---------- threefry2x32 cipher, exact JAX rotation/key schedule ----------
__host__ __device__ inline void tf2x32(uint32_t k0, uint32_t k1,
                                       uint32_t x0, uint32_t x1,
                                       uint32_t& o0, uint32_t& o1) {
  uint32_t ks2 = k0 ^ k1 ^ 0x1BD11BDAu;
  uint32_t v0 = x0 + k0, v1 = x1 + k1;
#define TF_R(r) { v0 += v1; v1 = rotl32(v1, r); v1 ^= v0; }
  TF_R(13) TF_R(15) TF_R(26) TF_R(6)
  v0 += k1;  v1 += ks2 + 1u;
  TF_R(17) TF_R(29) TF_R(16) TF_R(24)
  v0 += ks2; v1 += k0 + 2u;
  TF_R(13) TF_R(15) TF_R(26) TF_R(6)
  v0 += k0;  v1 += k1 + 3u;
  TF_R(17) TF_R(29) TF_R(16) TF_R(24)
  v0 += k1;  v1 += ks2 + 4u;
  TF_R(13) TF_R(15) TF_R(26) TF_R(6)
  v0 += ks2; v1 += k0 + 5u;
#undef TF_R
  o0 = v0; o1 = v1;
}

// scalar-friendly variant (uniform inputs -> SALU lowering)
__device__ inline uint32_t rbits_s(uint32_t k0, uint32_t k1, uint32_t i) {
  uint32_t ks2 = k0 ^ k1 ^ 0x1BD11BDAu;
  uint32_t v0 = k0, v1 = i + k1;
#define TF_S(r) { v0 += v1; v1 = rotl32s(v1, r); v1 ^= v0; }
  TF_S(13) TF_S(15) TF_S(26) TF_S(6)
  v0 += k1;  v1 += ks2 + 1u;
  TF_S(17) TF_S(29) TF_S(16) TF_S(24)
  v0 += ks2; v1 += k0 + 2u;
  TF_S(13) TF_S(15) TF_S(26) TF_S(6)
  v0 += k0;  v1 += k1 + 3u;
  TF_S(17) TF_S(29) TF_S(16) TF_S(24)
  v0 += k1;  v1 += ks2 + 4u;
  TF_S(13) TF_S(15) TF_S(26) TF_S(6)
  v0 += ks2; v1 += k0 + 5u;
#undef TF_S
  return v0 ^ v1;
}

// partitionable-threefry random bits for flat index i (hi word of iota = 0)
__device__ inline uint32_t rbits(uint32_t k0, uint32_t k1, uint32_t i) {
  uint32_t o0, o1;
  tf2x32(k0, k1, 0u, i, o0, o1);
  return o0 ^ o1;
}

__device__ inline uint32_t laneid() {
  return __builtin_amdgcn_mbcnt_hi(~0u, __builtin_amdgcn_mbcnt_lo(~0u, 0u));
}

// FI forward, ballot + scalar on-demand pb cipher. Bit-identical to the
// reference: integer flip test == f32 uniform compare; mask==0 int round-trip
// is the identity (so the branchless path equals q*scale when no flip);
// sext8 == qf>=128?qf-256:qf. The pb cipher runs once per FLIPPED lane on
// the SALU pipe (uniform after readlane) instead of 64-wide on the VALU.
__device__ inline float fi_fwd_ballot(float x, float scale, uint32_t ub,
                                      uint32_t kp0, uint32_t kp1, uint32_t i0) {
#pragma clang fp contract(off)
  float q = rintf(x / scale);                    // round-half-even, IEEE div
  q = fminf(127.0f, fmaxf(-128.0f, q));
  bool flip = ub < FLIP_LT;
  uint32_t pb = 0u;
  unsigned long long m = __ballot(flip);         // wave-uniform mask
  uint32_t lid = laneid();
  while (m) {                                    // rare (~0.5 flips / wave-batch)
    uint32_t L = (uint32_t)__builtin_ctzll(m);
    uint32_t i0s = __builtin_amdgcn_readlane(i0, L);   // scalar i0
    uint32_t pbs = rbits_s(kp0, kp1, i0s);             // SALU cipher
    pb = (lid == L) ? pbs : pb;
    m &= (m - 1);
  }
  uint32_t qt = ((uint32_t)(int)q) & 0xFFu;
  uint32_t qf = qt ^ (flip ? (1u << (pb & 7u)) : 0u);
  float y = (float)(int)(signed char)qf * scale; // == q*scale when no flip
  return x + (y - x);                            // x + stop_grad(y - x)
}

// legacy helper (fallback kernels only)
__device__ inline float fi_fwd_skip(float x, float scale,
                                    uint32_t ub, uint32_t kp0, uint32_t kp1,
                                    uint32_t i0) {
#pragma clang fp contract(off)
  float q = rintf(x / scale);
  q = fminf(127.0f, fmaxf(-128.0f, q));
  bool flip = ub < FLIP_LT;
  float y;
  if (__any(flip)) {
    uint32_t pb = rbits(kp0, kp1, i0);
    uint32_t qt = ((uint32_t)(int)q) & 0xFFu;
    uint32_t mask = flip ? (1u << (pb & 7u)) : 0u;
    uint32_t qf = qt ^ mask;
    float qs = (float)(int)(signed char)(qf);
    y = qs * scale;
  } else {
    y = q * scale;
  }
  return x + (y - x);
}

template <int BS>
__device__ inline float block_max(float v) {
  __shared__ float s[BS];
  int t = threadIdx.x;
  __syncthreads();
  s[t] = v; __syncthreads();
  for (int o = BS / 2; o > 0; o >>= 1) {
    if (t < o) s[t] = fmaxf(s[t], s[t + o]);
    __syncthreads();
  }
  return s[0];
}

// ---------- kernel 1: quantize weights (_quant_ste forward) ----------
__global__ __launch_bounds__(256) void k_prep(const float* __restrict__ w,
                                              float* __restrict__ wq) {
#pragma clang fp contract(off)
  float m = 0.f;
  for (int i = threadIdx.x; i < CO * KK; i += 256) m = fmaxf(m, fabsf(w[i]));
  m = block_max<256>(m);
  float scale = m / 127.0f + 1e-12f;
  for (int i = threadIdx.x; i < CO * KK; i += 256) {
    float xv = w[i];
    float q = fminf(127.0f, fmaxf(-128.0f, rintf(xv / scale)));
    float y = q * scale;
    wq[i] = xv + (y - xv);
  }
}

// ---------- kernel 2: max|p| = max_k (max_l|xc[l,k]| * max_co|wq[co,k]|) ----------
__global__ __launch_bounds__(256) void k_maxp(const float* __restrict__ x,
                                              const float* __restrict__ wq,
                                              unsigned int* __restrict__ maxp_bits) {
#pragma clang fp contract(off)
  int k = blockIdx.x;                       // 0..287
  int ci = k / 9, r = k % 9, di = r / 3, dj = r % 3;
  const float* xr = x + ci * LL;
  float mx = 0.f;
  for (int l = threadIdx.x; l < LL; l += 256) {
    int oy = l / WW, ox = l % WW;
    int yy = oy + di - 1, xx = ox + dj - 1;
    float v = (yy >= 0 && yy < HH && xx >= 0 && xx < WW) ? xr[yy * WW + xx] : 0.f;
    mx = fmaxf(mx, fabsf(v));
  }
  float mw = 0.f;
  for (int co = threadIdx.x; co < CO; co += 256) mw = fmaxf(mw, fabsf(wq[co * KK + k]));
  mx = block_max<256>(mx);
  mw = block_max<256>(mw);
  if (threadIdx.x == 0) atomicMax(maxp_bits, __float_as_uint(mx * mw));
}

// ---------- k_fi1cs: fused FI1 + serial cumsum, double-pumped LDS tile ----------
__global__ __launch_bounds__(256) void k_fi1cs(const float* __restrict__ x,
                                               const float* __restrict__ wq,
                                               const unsigned int* __restrict__ scal,
                                               unsigned int* __restrict__ maxc_bits,
                                               float* __restrict__ cws,
                                               uint32_t ku0, uint32_t ku1,
                                               uint32_t kp0, uint32_t kp1) {
#pragma clang fp contract(off)
  __shared__ float sW[KK];                  // 1152 B
  __shared__ float sP[KH][TO];              // 18432 B
  int tid = threadIdx.x;
  uint32_t outi0 = blockIdx.x * (uint32_t)TO;
  int co = (int)(outi0 / (uint32_t)LL);     // block-uniform (32 | 3136)
  for (int i = tid; i < KK; i += 256) sW[i] = wq[co * KK + i];
  __syncthreads();

  int o = tid & 31, s = tid >> 5;           // s in 0..7
  uint32_t outi = outi0 + (uint32_t)o;
  int l = (int)(outi - (uint32_t)co * LL);
  int oy = l / WW, ox = l % WW;
  float scale_p = __uint_as_float(scal[1]) / 127.0f + 1e-12f;
  uint32_t ibase = outi * (uint32_t)KK;

  float carry = 0.f, maxc = 0.f;
  for (int half = 0; half < 2; ++half) {
    int kbase = half * KH;
    int k = kbase + s * 18;
    int ci0 = k / 9;                        // = 16*half + 2*s
    for (int c2 = 0; c2 < 2; ++c2) {
      const float* xr = x + (ci0 + c2) * LL;
      float xv[9];
      uint32_t ub[9];
#pragma unroll
      for (int di = 0; di < 3; ++di) {
        int yy = oy + di - 1;
        bool yok = (yy >= 0) && (yy < HH);
#pragma unroll
        for (int dj = 0; dj < 3; ++dj) {
          int xx = ox + dj - 1;
          xv[di * 3 + dj] = (yok && xx >= 0 && xx < WW) ? xr[yy * WW + xx] : 0.f;
        }
      }
#pragma unroll
      for (int j = 0; j < 9; ++j)           // 9 independent cipher chains
        ub[j] = rbits(ku0, ku1, ibase + (uint32_t)(k + j));
#pragma unroll
      for (int j = 0; j < 9; ++j) {
        float p = xv[j] * sW[k + j];
        sP[k + j - kbase][o] = fi_fwd_ballot(p, scale_p, ub[j], kp0, kp1,
                                             ibase + (uint32_t)(k + j));
      }
      k += 9;
    }
    __syncthreads();
    // Phase 2: lanes 0..31 fold this half's 144 rows, carry held in register.
    if (tid < TO) {
      float c = carry;
#pragma unroll 8
      for (int kk = 0; kk < KH; ++kk) {
        c += sP[kk][tid];                   // exact reference fold order
        sP[kk][tid] = c;
        maxc = fmaxf(maxc, fabsf(c));
      }
      carry = c;
    }
    __syncthreads();
    // Phase 3: coalesced write-out (rows of 32 consecutive outi).
    for (int kk = s; kk < KH; kk += 8)
      cws[(uint32_t)(kbase + kk) * NOUT + outi0 + (uint32_t)o] = sP[kk][o];
    __syncthreads();                        // next half overwrites sP
  }
  // maxc lives in lanes 0..31 of wave 0; lanes 32..63 hold 0 -> full-wave reduce.
  if (tid < 64) {
#pragma unroll
    for (int off = 32; off > 0; off >>= 1)
      maxc = fmaxf(maxc, __shfl_down(maxc, off));
    if (tid == 0) atomicMax(maxc_bits, __float_as_uint(maxc));
  }
}

// ---------- k_fi2split: FI2 on c, in-block k-split, 8-way cipher batching ----
__global__ __launch_bounds__(256) void k_fi2split(const float* __restrict__ cws,
                                                  const unsigned int* __restrict__ scal,
                                                  unsigned int* __restrict__ maxy_bits,
                                                  float* __restrict__ yout,
                                                  uint32_t ku0, uint32_t ku1,
                                                  uint32_t kp0, uint32_t kp1) {
#pragma clang fp contract(off)
  __shared__ float sE[KG][64];
  __shared__ float sYs[64];
  int tid = threadIdx.x;
  int lane = tid & 63;
  int kg = tid >> 6;                               // 0..3
  uint32_t outi = blockIdx.x * 64u + (uint32_t)lane;   // 3136*64 = NOUT exact
  float scale_c = __uint_as_float(scal[2]) / 127.0f + 1e-12f;
  int ks = (kg == 0) ? 1 : kg * KCH;
  int ke = (kg == KG - 1) ? (KK - 1) : (kg * KCH + KCH);
  const float* cp = cws + (uint32_t)ks * NOUT + outi;
  uint32_t i0 = outi * (uint32_t)KK + (uint32_t)ks;
  float e = 0.f;
  int k = ks;
  while (k + 8 <= ke) {
    float c8[8];
    uint32_t ub[8];
#pragma unroll
    for (int j = 0; j < 8; ++j) c8[j] = cp[(uint32_t)j * NOUT];  // issue loads
#pragma unroll
    for (int j = 0; j < 8; ++j) ub[j] = rbits(ku0, ku1, i0 + (uint32_t)j);
#pragma unroll
    for (int j = 0; j < 8; ++j) {
      float cf = fi_fwd_ballot(c8[j], scale_c, ub[j], kp0, kp1, i0 + (uint32_t)j);
      e += (cf - c8[j]);
    }
    cp += 8u * NOUT; i0 += 8; k += 8;
  }
  for (; k < ke; ++k) {
    float c = *cp; cp += NOUT;
    uint32_t ub = rbits(ku0, ku1, i0);
    float cf = fi_fwd_ballot(c, scale_c, ub, kp0, kp1, i0);
    e += (cf - c);
    ++i0;
  }
  sE[kg][lane] = e;
  if (kg == KG - 1) {                              // k = 287 -> ys
    float c = *cp;
    uint32_t ub = rbits(ku0, ku1, i0);
    float cf = fi_fwd_ballot(c, scale_c, ub, kp0, kp1, i0);
    sYs[lane] = cf;
  }
  __syncthreads();
  float maxy = 0.f;
  if (tid < 64) {
    float ee = ((sE[0][lane] + sE[1][lane]) + sE[2][lane]) + sE[3][lane];
    float y = sYs[lane] + ee;
    yout[outi] = y;
    maxy = fabsf(y);
  }
  maxy = block_max<256>(maxy);
  if (tid == 0) atomicMax(maxy_bits, __float_as_uint(maxy));
}

// ---------- fallback (small ws): fused FI1+cumsum, then recompute-FI2 ----------
__global__ __launch_bounds__(64) void k_passC_nostore(const float* __restrict__ x,
                                                      const float* __restrict__ wq,
                                                      const unsigned int* __restrict__ scal,
                                                      unsigned int* __restrict__ maxc_bits,
                                                      uint32_t ku0, uint32_t ku1,
                                                      uint32_t kp0, uint32_t kp1) {
#pragma clang fp contract(off)
  __shared__ float sW[KK];
  int co = blockIdx.y;
  for (int i = threadIdx.x; i < KK; i += 64) sW[i] = wq[co * KK + i];
  __syncthreads();
  int l = blockIdx.x * 64 + threadIdx.x;
  float maxc = 0.f;
  if (l < LL) {
    float scale_p = __uint_as_float(scal[1]) / 127.0f + 1e-12f;
    int oy = l / WW, ox = l % WW;
    uint32_t base = (uint32_t)(co * LL + l) * KK;
    float c = 0.f;
    int k = 0;
    for (int ci = 0; ci < CI; ++ci) {
      const float* xr = x + ci * LL;
#pragma unroll
      for (int di = 0; di < 3; ++di) {
        int yy = oy + di - 1;
        bool yok = (yy >= 0) && (yy < HH);
#pragma unroll
        for (int dj = 0; dj < 3; ++dj, ++k) {
          int xx = ox + dj - 1;
          float xv = (yok && xx >= 0 && xx < WW) ? xr[yy * WW + xx] : 0.f;
          float p = xv * sW[k];
          uint32_t i0 = base + (uint32_t)k;
          uint32_t ub = rbits(ku0, ku1, i0);
          c += fi_fwd_skip(p, scale_p, ub, kp0, kp1, i0);
          maxc = fmaxf(maxc, fabsf(c));
        }
      }
    }
  }
  maxc = block_max<64>(maxc);
  if (threadIdx.x == 0) atomicMax(maxc_bits, __float_as_uint(maxc));
}

__global__ __launch_bounds__(256) void k_passD_rec(const float* __restrict__ x,
                                                   const float* __restrict__ wq,
                                                   const unsigned int* __restrict__ scal,
                                                   unsigned int* __restrict__ maxy_bits,
                                                   float* __restrict__ yout,
                                                   uint32_t ku10, uint32_t ku11,
                                                   uint32_t kp10, uint32_t kp11,
                                                   uint32_t ku20, uint32_t ku21,
                                                   uint32_t kp20, uint32_t kp21) {
#pragma clang fp contract(off)
  __shared__ float sW[KK];
  int co = blockIdx.y;
  for (int i = threadIdx.x; i < KK; i += 256) sW[i] = wq[co * KK + i];
  __syncthreads();
  int l = blockIdx.x * 256 + threadIdx.x;
  float maxy = 0.f;
  if (l < LL) {
    float scale_p = __uint_as_float(scal[1]) / 127.0f + 1e-12f;
    float scale_c = __uint_as_float(scal[2]) / 127.0f + 1e-12f;
    int oy = l / WW, ox = l % WW;
    uint32_t base = (uint32_t)(co * LL + l) * KK;
    float c = 0.f, e = 0.f, ys = 0.f;
    int k = 0;
    for (int ci = 0; ci < CI; ++ci) {
      const float* xr = x + ci * LL;
#pragma unroll
      for (int di = 0; di < 3; ++di) {
        int yy = oy + di - 1;
        bool yok = (yy >= 0) && (yy < HH);
#pragma unroll
        for (int dj = 0; dj < 3; ++dj, ++k) {
          int xx = ox + dj - 1;
          float xv = (yok && xx >= 0 && xx < WW) ? xr[yy * WW + xx] : 0.f;
          float p = xv * sW[k];
          uint32_t i0 = base + (uint32_t)k;
          uint32_t ub1 = rbits(ku10, ku11, i0);
          c += fi_fwd_skip(p, scale_p, ub1, kp10, kp11, i0);
          uint32_t ub2 = rbits(ku20, ku21, i0);
          float cf = fi_fwd_skip(c, scale_c, ub2, kp20, kp21, i0);
          if (k >= 1 && k <= 286) e += (cf - c);
          if (k == 287)           ys = cf;
        }
      }
    }
    float y = ys + e;
    yout[co * LL + l] = y;
    maxy = fabsf(y);
  }
  maxy = block_max<256>(maxy);
  if (threadIdx.x == 0) atomicMax(maxy_bits, __float_as_uint(maxy));
}

// ---------- pass E: FI3 on y, in place in d_out ----------
__global__ __launch_bounds__(256) void k_passE(float* __restrict__ y,
                                               const unsigned int* __restrict__ scal,
                                               uint32_t ku0, uint32_t ku1,
                                               uint32_t kp0, uint32_t kp1) {
#pragma clang fp contract(off)
  uint32_t i = blockIdx.x * 256u + threadIdx.x;
  float scale_y = __uint_as_float(scal[3]) / 127.0f + 1e-12f;
  uint32_t ub = rbits(ku0, ku1, i);
  y[i] = fi_fwd_ballot(y[i], scale_y, ub, kp0, kp1, i);
}

extern "C" void kernel_launch(void* const* d_in, const int* in_sizes, int n_in,
                              void* d_out, int out_size, void* d_ws, size_t ws_size,
                              hipStream_t stream) {
  const float* x = (const float*)d_in[0];   // (1,32,56,56)
  const float* w = (const float*)d_in[1];   // (64,32,3,3)
  float* out = (float*)d_out;               // (1,64,56,56)

  unsigned int* scal = (unsigned int*)d_ws; // [1]=max|p| [2]=max|c| [3]=max|y|
  float* wq = (float*)d_ws + 16;            // 18432 floats
  float* cws = (float*)d_ws + CWS_OFF_FLOATS;
  bool bigws = ws_size >= WS_NEED;          // constant across calls -> graph-safe

  // ---- exact JAX key derivation, partitionable threefry ----
  uint32_t K1[2], K2[2], K3[2];
  tf2x32(0u, 42u, 0u, 0u, K1[0], K1[1]);    // split(key(42), 3)
  tf2x32(0u, 42u, 0u, 1u, K2[0], K2[1]);
  tf2x32(0u, 42u, 0u, 2u, K3[0], K3[1]);
  auto derive = [](const uint32_t kk[2], uint32_t U[2], uint32_t P[2]) {
    uint32_t kA0, kA1, kB0, kB1, t0, t1;
    tf2x32(kk[0], kk[1], 0u, 0u, kA0, kA1); // split(key,2)[0] -> uniform key
    tf2x32(kk[0], kk[1], 0u, 1u, kB0, kB1); // split(key,2)[1] -> randint key
    U[0] = kA0; U[1] = kA1;
    tf2x32(kB0, kB1, 0u, 1u, t0, t1);       // randint lower-bits key
    P[0] = t0; P[1] = t1;
  };
  uint32_t U1[2],P1[2],U2[2],P2[2],U3[2],P3[2];
  derive(K1, U1, P1); derive(K2, U2, P2); derive(K3, U3, P3);

  hipMemsetAsync(d_ws, 0, 64, stream);      // zero the atomic-max slots

  k_prep<<<1, 256, 0, stream>>>(w, wq);
  k_maxp<<<KK, 256, 0, stream>>>(x, wq, scal + 1);
  if (bigws) {
    k_fi1cs<<<NOUT / TO, 256, 0, stream>>>(x, wq, scal, scal + 2, cws,
                                           U1[0], U1[1], P1[0], P1[1]);
    k_fi2split<<<3136, 256, 0, stream>>>(cws, scal, scal + 3, out,
                                         U2[0], U2[1], P2[0], P2[1]);
  } else {
    dim3 gC(49, 64);
    k_passC_nostore<<<gC, 64, 0, stream>>>(x, wq, scal, scal + 2,
                                           U1[0], U1[1], P1[0], P1[1]);
    dim3 gR(13, 64);
    k_passD_rec<<<gR, 256, 0, stream>>>(x, wq, scal, scal + 3, out,
                                        U1[0], U1[1], P1[0], P1[1],
                                        U2[0], U2[1], P2[0], P2[1]);
  }
  k_passE<<<NOUT / 256, 256, 0, stream>>>(out, scal,
                                          U3[0], U3[1], P3[0], P3[1]);
}

// Round 11
// 430.523 us; speedup vs baseline: 1.1183x; 1.1183x over previous
//
#include <hip/hip_runtime.h>
#include <cstdint>

#define CO   64
#define CI   32
#define HH   56
#define WW   56
#define LL   3136        // 56*56
#define KK   288         // 32*9
#define KH   144         // KK/2 — double-pumped LDS tile
#define NOUT 200704u     // 64*3136
#define KG   4           // k-groups per output element in fi2
#define TO   32          // outi-tile per block in fused fi1+cumsum
#define NB   36          // 288/8 float8 batches

// flip threshold: u < 0.008f  <=>  (ub>>9) <= 67108  <=>  ub < 67109*512
#define FLIP_LT 34359808u

// workspace layout: [0..63] atomic-max slots | 64.. wq (73728 B) | 81920.. c_ws
// c_ws layout: float8 batches — c[k][outi] stored at [(k/8)*NOUT + outi]*8 + k%8
#define CWS_OFF_FLOATS 20480u                 // 81920 / 4
#define WS_NEED (81920ull + 4ull * 288ull * 200704ull)

__host__ __device__ inline uint32_t rotl32(uint32_t v, uint32_t r) {
#ifdef __HIP_DEVICE_COMPILE__
  return __builtin_amdgcn_alignbit(v, v, 32u - r);   // (v:v)>>(32-r) = rotl(v,r)
#else
  return (v << r) | (v >> (32u - r));
#endif
}

// ---------- threefry2x32 cipher, exact JAX rotation/key schedule ----------
__host__ __device__ inline void tf2x32(uint32_t k0, uint32_t k1,
                                       uint32_t x0, uint32_t x1,
                                       uint32_t& o0, uint32_t& o1) {
  uint32_t ks2 = k0 ^ k1 ^ 0x1BD11BDAu;
  uint32_t v0 = x0 + k0, v1 = x1 + k1;
#define TF_R(r) { v0 += v1; v1 = rotl32(v1, r); v1 ^= v0; }
  TF_R(13) TF_R(15) TF_R(26) TF_R(6)
  v0 += k1;  v1 += ks2 + 1u;
  TF_R(17) TF_R(29) TF_R(16) TF_R(24)
  v0 += ks2; v1 += k0 + 2u;
  TF_R(13) TF_R(15) TF_R(26) TF_R(6)
  v0 += k0;  v1 += k1 + 3u;
  TF_R(17) TF_R(29) TF_R(16) TF_R(24)
  v0 += k1;  v1 += ks2 + 4u;
  TF_R(13) TF_R(15) TF_R(26) TF_R(6)
  v0 += ks2; v1 += k0 + 5u;
#undef TF_R
  o0 = v0; o1 = v1;
}

// partitionable-threefry random bits for flat index i (hi word of iota = 0)
__device__ inline uint32_t rbits(uint32_t k0, uint32_t k1, uint32_t i) {
  uint32_t o0, o1;
  tf2x32(k0, k1, 0u, i, o0, o1);
  return o0 ^ o1;
}

// FI forward with wave-level pos-cipher skip. Bit-identical to the reference:
// integer flip test == f32 uniform compare; mask==0 int round-trip is the
// identity so the skip path y = q*scale is exact; sext8 == qf>=128?qf-256:qf.
__device__ inline float fi_fwd_skip(float x, float scale,
                                    uint32_t ub, uint32_t kp0, uint32_t kp1,
                                    uint32_t i0) {
#pragma clang fp contract(off)
  float q = rintf(x / scale);                    // round-half-even, IEEE div
  q = fminf(127.0f, fmaxf(-128.0f, q));
  bool flip = ub < FLIP_LT;
  float y;
  if (__any(flip)) {                             // wave-uniform branch
    uint32_t pb = rbits(kp0, kp1, i0);
    uint32_t qt = ((uint32_t)(int)q) & 0xFFu;
    uint32_t mask = flip ? (1u << (pb & 7u)) : 0u;
    uint32_t qf = qt ^ mask;
    float qs = (float)(int)(signed char)(qf);
    y = qs * scale;
  } else {
    y = q * scale;
  }
  return x + (y - x);                            // x + stop_grad(y - x)
}

template <int BS>
__device__ inline float block_max(float v) {
  __shared__ float s[BS];
  int t = threadIdx.x;
  __syncthreads();
  s[t] = v; __syncthreads();
  for (int o = BS / 2; o > 0; o >>= 1) {
    if (t < o) s[t] = fmaxf(s[t], s[t + o]);
    __syncthreads();
  }
  return s[0];
}

// ---------- kernel 1: quantize weights (_quant_ste forward) ----------
__global__ __launch_bounds__(256) void k_prep(const float* __restrict__ w,
                                              float* __restrict__ wq) {
#pragma clang fp contract(off)
  float m = 0.f;
  for (int i = threadIdx.x; i < CO * KK; i += 256) m = fmaxf(m, fabsf(w[i]));
  m = block_max<256>(m);
  float scale = m / 127.0f + 1e-12f;
  for (int i = threadIdx.x; i < CO * KK; i += 256) {
    float xv = w[i];
    float q = fminf(127.0f, fmaxf(-128.0f, rintf(xv / scale)));
    float y = q * scale;
    wq[i] = xv + (y - xv);
  }
}

// ---------- kernel 2: max|p| = max_k (max_l|xc[l,k]| * max_co|wq[co,k]|) ----------
__global__ __launch_bounds__(256) void k_maxp(const float* __restrict__ x,
                                              const float* __restrict__ wq,
                                              unsigned int* __restrict__ maxp_bits) {
#pragma clang fp contract(off)
  int k = blockIdx.x;                       // 0..287
  int ci = k / 9, r = k % 9, di = r / 3, dj = r % 3;
  const float* xr = x + ci * LL;
  float mx = 0.f;
  for (int l = threadIdx.x; l < LL; l += 256) {
    int oy = l / WW, ox = l % WW;
    int yy = oy + di - 1, xx = ox + dj - 1;
    float v = (yy >= 0 && yy < HH && xx >= 0 && xx < WW) ? xr[yy * WW + xx] : 0.f;
    mx = fmaxf(mx, fabsf(v));
  }
  float mw = 0.f;
  for (int co = threadIdx.x; co < CO; co += 256) mw = fmaxf(mw, fabsf(wq[co * KK + k]));
  mx = block_max<256>(mx);
  mw = block_max<256>(mw);
  if (threadIdx.x == 0) atomicMax(maxp_bits, __float_as_uint(mx * mw));
}

// ---------- k_fi1cs: fused FI1 + serial cumsum, double-pumped LDS tile ----------
// LDS ~19.6KB -> high occupancy. 288-fold = two 144-folds, carry in register.
// Phase 3 writes c in the float8-batch layout via float4-pair stores.
__global__ __launch_bounds__(256) void k_fi1cs(const float* __restrict__ x,
                                               const float* __restrict__ wq,
                                               const unsigned int* __restrict__ scal,
                                               unsigned int* __restrict__ maxc_bits,
                                               float* __restrict__ cws,
                                               uint32_t ku0, uint32_t ku1,
                                               uint32_t kp0, uint32_t kp1) {
#pragma clang fp contract(off)
  __shared__ float sW[KK];                  // 1152 B
  __shared__ float sP[KH][TO];              // 18432 B
  int tid = threadIdx.x;
  uint32_t outi0 = blockIdx.x * (uint32_t)TO;
  int co = (int)(outi0 / (uint32_t)LL);     // block-uniform (32 | 3136)
  for (int i = tid; i < KK; i += 256) sW[i] = wq[co * KK + i];
  __syncthreads();

  int o = tid & 31, s = tid >> 5;           // s in 0..7
  uint32_t outi = outi0 + (uint32_t)o;
  int l = (int)(outi - (uint32_t)co * LL);
  int oy = l / WW, ox = l % WW;
  float scale_p = __uint_as_float(scal[1]) / 127.0f + 1e-12f;
  uint32_t ibase = outi * (uint32_t)KK;

  float carry = 0.f, maxc = 0.f;
  for (int half = 0; half < 2; ++half) {
    int kbase = half * KH;
    int k = kbase + s * 18;
    int ci0 = k / 9;                        // = 16*half + 2*s
    for (int c2 = 0; c2 < 2; ++c2) {
      const float* xr = x + (ci0 + c2) * LL;
      float xv[9];
      uint32_t ub[9];
#pragma unroll
      for (int di = 0; di < 3; ++di) {
        int yy = oy + di - 1;
        bool yok = (yy >= 0) && (yy < HH);
#pragma unroll
        for (int dj = 0; dj < 3; ++dj) {
          int xx = ox + dj - 1;
          xv[di * 3 + dj] = (yok && xx >= 0 && xx < WW) ? xr[yy * WW + xx] : 0.f;
        }
      }
#pragma unroll
      for (int j = 0; j < 9; ++j)           // 9 independent cipher chains
        ub[j] = rbits(ku0, ku1, ibase + (uint32_t)(k + j));
#pragma unroll
      for (int j = 0; j < 9; ++j) {
        float p = xv[j] * sW[k + j];
        sP[k + j - kbase][o] = fi_fwd_skip(p, scale_p, ub[j], kp0, kp1,
                                           ibase + (uint32_t)(k + j));
      }
      k += 9;
    }
    __syncthreads();
    // Phase 2: lanes 0..31 fold this half's 144 rows, carry held in register.
    if (tid < TO) {
      float c = carry;
#pragma unroll 8
      for (int kk = 0; kk < KH; ++kk) {
        c += sP[kk][tid];                   // exact reference fold order
        sP[kk][tid] = c;
        maxc = fmaxf(maxc, fabsf(c));
      }
      carry = c;
    }
    __syncthreads();
    // Phase 3: write-out, float8-batch layout, float4-pair vector stores.
    for (int b = s; b < 18; b += 8) {
      int gb = half * 18 + b;
      float4 v0 = {sP[b * 8 + 0][o], sP[b * 8 + 1][o],
                   sP[b * 8 + 2][o], sP[b * 8 + 3][o]};
      float4 v1 = {sP[b * 8 + 4][o], sP[b * 8 + 5][o],
                   sP[b * 8 + 6][o], sP[b * 8 + 7][o]};
      float* op = cws + ((size_t)gb * NOUT + outi) * 8u;
      *(float4*)op = v0;
      *((float4*)op + 1) = v1;
    }
    __syncthreads();                        // next half overwrites sP
  }
  // maxc lives in lanes 0..31 of wave 0; lanes 32..63 hold 0 -> full-wave reduce.
  if (tid < 64) {
#pragma unroll
    for (int off = 32; off > 0; off >>= 1)
      maxc = fmaxf(maxc, __shfl_down(maxc, off));
    if (tid == 0) atomicMax(maxc_bits, __float_as_uint(maxc));
  }
}

// ---------- fi2 batch helper: 8 contiguous c's, vector load, no per-elem branches
// J0: first j processed (1 for the k=0 batch). YS: j=7 is k=287 -> ys.
template <int J0, bool YS>
__device__ inline void fi2_batch(const float* __restrict__ bp, uint32_t ib,
                                 float scale_c,
                                 uint32_t ku0, uint32_t ku1,
                                 uint32_t kp0, uint32_t kp1,
                                 float& e, float& ys) {
#pragma clang fp contract(off)
  float4 A = *(const float4*)bp;
  float4 B = *(const float4*)(bp + 4);
  float c8[8] = {A.x, A.y, A.z, A.w, B.x, B.y, B.z, B.w};
  uint32_t ub[8];
#pragma unroll
  for (int j = J0; j < 8; ++j) ub[j] = rbits(ku0, ku1, ib + (uint32_t)j);
#pragma unroll
  for (int j = J0; j < 8; ++j) {
    float cf = fi_fwd_skip(c8[j], scale_c, ub[j], kp0, kp1, ib + (uint32_t)j);
    if (YS && j == 7) ys = cf;
    else             e += (cf - c8[j]);
  }
}

// ---------- k_fi2split: FI2 on c, in-block k-split, float8-batch loads ----------
// Block = 4 waves; wave kg handles 9 batches (72 k's) for 64 consecutive outi.
// Same chunk boundaries and within-thread k-order as before -> same e association.
__global__ __launch_bounds__(256) void k_fi2split(const float* __restrict__ cws,
                                                  const unsigned int* __restrict__ scal,
                                                  unsigned int* __restrict__ maxy_bits,
                                                  float* __restrict__ yout,
                                                  uint32_t ku0, uint32_t ku1,
                                                  uint32_t kp0, uint32_t kp1) {
#pragma clang fp contract(off)
  __shared__ float sE[KG][64];
  __shared__ float sYs[64];
  int tid = threadIdx.x;
  int lane = tid & 63;
  int kg = tid >> 6;                               // 0..3
  uint32_t outi = blockIdx.x * 64u + (uint32_t)lane;   // 3136*64 = NOUT exact
  float scale_c = __uint_as_float(scal[2]) / 127.0f + 1e-12f;
  uint32_t ibb = outi * (uint32_t)KK;
  const float* bp0 = cws + (size_t)outi * 8u;
  float e = 0.f, ys = 0.f;
  if (kg == 0) {
    fi2_batch<1, false>(bp0, ibb, scale_c, ku0, ku1, kp0, kp1, e, ys);
    for (int b = 1; b < 9; ++b)
      fi2_batch<0, false>(bp0 + (size_t)b * NOUT * 8u, ibb + (uint32_t)b * 8u,
                          scale_c, ku0, ku1, kp0, kp1, e, ys);
  } else if (kg == KG - 1) {
    for (int b = 27; b < 35; ++b)
      fi2_batch<0, false>(bp0 + (size_t)b * NOUT * 8u, ibb + (uint32_t)b * 8u,
                          scale_c, ku0, ku1, kp0, kp1, e, ys);
    fi2_batch<0, true>(bp0 + (size_t)35 * NOUT * 8u, ibb + 280u,
                       scale_c, ku0, ku1, kp0, kp1, e, ys);
  } else {
    int b0 = kg * 9;
    for (int b = b0; b < b0 + 9; ++b)
      fi2_batch<0, false>(bp0 + (size_t)b * NOUT * 8u, ibb + (uint32_t)b * 8u,
                          scale_c, ku0, ku1, kp0, kp1, e, ys);
  }
  sE[kg][lane] = e;
  if (kg == KG - 1) sYs[lane] = ys;
  __syncthreads();
  float maxy = 0.f;
  if (tid < 64) {
    float ee = ((sE[0][lane] + sE[1][lane]) + sE[2][lane]) + sE[3][lane];
    float y = sYs[lane] + ee;
    yout[outi] = y;
    maxy = fabsf(y);
  }
  maxy = block_max<256>(maxy);
  if (tid == 0) atomicMax(maxy_bits, __float_as_uint(maxy));
}

// ---------- fallback (small ws): fused FI1+cumsum, then recompute-FI2 ----------
__global__ __launch_bounds__(64) void k_passC_nostore(const float* __restrict__ x,
                                                      const float* __restrict__ wq,
                                                      const unsigned int* __restrict__ scal,
                                                      unsigned int* __restrict__ maxc_bits,
                                                      uint32_t ku0, uint32_t ku1,
                                                      uint32_t kp0, uint32_t kp1) {
#pragma clang fp contract(off)
  __shared__ float sW[KK];
  int co = blockIdx.y;
  for (int i = threadIdx.x; i < KK; i += 64) sW[i] = wq[co * KK + i];
  __syncthreads();
  int l = blockIdx.x * 64 + threadIdx.x;
  float maxc = 0.f;
  if (l < LL) {
    float scale_p = __uint_as_float(scal[1]) / 127.0f + 1e-12f;
    int oy = l / WW, ox = l % WW;
    uint32_t base = (uint32_t)(co * LL + l) * KK;
    float c = 0.f;
    int k = 0;
    for (int ci = 0; ci < CI; ++ci) {
      const float* xr = x + ci * LL;
#pragma unroll
      for (int di = 0; di < 3; ++di) {
        int yy = oy + di - 1;
        bool yok = (yy >= 0) && (yy < HH);
#pragma unroll
        for (int dj = 0; dj < 3; ++dj, ++k) {
          int xx = ox + dj - 1;
          float xv = (yok && xx >= 0 && xx < WW) ? xr[yy * WW + xx] : 0.f;
          float p = xv * sW[k];
          uint32_t i0 = base + (uint32_t)k;
          uint32_t ub = rbits(ku0, ku1, i0);
          c += fi_fwd_skip(p, scale_p, ub, kp0, kp1, i0);
          maxc = fmaxf(maxc, fabsf(c));
        }
      }
    }
  }
  maxc = block_max<64>(maxc);
  if (threadIdx.x == 0) atomicMax(maxc_bits, __float_as_uint(maxc));
}

__global__ __launch_bounds__(256) void k_passD_rec(const float* __restrict__ x,
                                                   const float* __restrict__ wq,
                                                   const unsigned int* __restrict__ scal,
                                                   unsigned int* __restrict__ maxy_bits,
                                                   float* __restrict__ yout,
                                                   uint32_t ku10, uint32_t ku11,
                                                   uint32_t kp10, uint32_t kp11,
                                                   uint32_t ku20, uint32_t ku21,
                                                   uint32_t kp20, uint32_t kp21) {
#pragma clang fp contract(off)
  __shared__ float sW[KK];
  int co = blockIdx.y;
  for (int i = threadIdx.x; i < KK; i += 256) sW[i] = wq[co * KK + i];
  __syncthreads();
  int l = blockIdx.x * 256 + threadIdx.x;
  float maxy = 0.f;
  if (l < LL) {
    float scale_p = __uint_as_float(scal[1]) / 127.0f + 1e-12f;
    float scale_c = __uint_as_float(scal[2]) / 127.0f + 1e-12f;
    int oy = l / WW, ox = l % WW;
    uint32_t base = (uint32_t)(co * LL + l) * KK;
    float c = 0.f, e = 0.f, ys = 0.f;
    int k = 0;
    for (int ci = 0; ci < CI; ++ci) {
      const float* xr = x + ci * LL;
#pragma unroll
      for (int di = 0; di < 3; ++di) {
        int yy = oy + di - 1;
        bool yok = (yy >= 0) && (yy < HH);
#pragma unroll
        for (int dj = 0; dj < 3; ++dj, ++k) {
          int xx = ox + dj - 1;
          float xv = (yok && xx >= 0 && xx < WW) ? xr[yy * WW + xx] : 0.f;
          float p = xv * sW[k];
          uint32_t i0 = base + (uint32_t)k;
          uint32_t ub1 = rbits(ku10, ku11, i0);
          c += fi_fwd_skip(p, scale_p, ub1, kp10, kp11, i0);
          uint32_t ub2 = rbits(ku20, ku21, i0);
          float cf = fi_fwd_skip(c, scale_c, ub2, kp20, kp21, i0);
          if (k >= 1 && k <= 286) e += (cf - c);
          if (k == 287)           ys = cf;
        }
      }
    }
    float y = ys + e;
    yout[co * LL + l] = y;
    maxy = fabsf(y);
  }
  maxy = block_max<256>(maxy);
  if (threadIdx.x == 0) atomicMax(maxy_bits, __float_as_uint(maxy));
}

// ---------- pass E: FI3 on y, in place in d_out ----------
__global__ __launch_bounds__(256) void k_passE(float* __restrict__ y,
                                               const unsigned int* __restrict__ scal,
                                               uint32_t ku0, uint32_t ku1,
                                               uint32_t kp0, uint32_t kp1) {
#pragma clang fp contract(off)
  uint32_t i = blockIdx.x * 256u + threadIdx.x;
  float scale_y = __uint_as_float(scal[3]) / 127.0f + 1e-12f;
  uint32_t ub = rbits(ku0, ku1, i);
  y[i] = fi_fwd_skip(y[i], scale_y, ub, kp0, kp1, i);
}

extern "C" void kernel_launch(void* const* d_in, const int* in_sizes, int n_in,
                              void* d_out, int out_size, void* d_ws, size_t ws_size,
                              hipStream_t stream) {
  const float* x = (const float*)d_in[0];   // (1,32,56,56)
  const float* w = (const float*)d_in[1];   // (64,32,3,3)
  float* out = (float*)d_out;               // (1,64,56,56)

  unsigned int* scal = (unsigned int*)d_ws; // [1]=max|p| [2]=max|c| [3]=max|y|
  float* wq = (float*)d_ws + 16;            // 18432 floats
  float* cws = (float*)d_ws + CWS_OFF_FLOATS;
  bool bigws = ws_size >= WS_NEED;          // constant across calls -> graph-safe

  // ---- exact JAX key derivation, partitionable threefry ----
  uint32_t K1[2], K2[2], K3[2];
  tf2x32(0u, 42u, 0u, 0u, K1[0], K1[1]);    // split(key(42), 3)
  tf2x32(0u, 42u, 0u, 1u, K2[0], K2[1]);
  tf2x32(0u, 42u, 0u, 2u, K3[0], K3[1]);
  auto derive = [](const uint32_t kk[2], uint32_t U[2], uint32_t P[2]) {
    uint32_t kA0, kA1, kB0, kB1, t0, t1;
    tf2x32(kk[0], kk[1], 0u, 0u, kA0, kA1); // split(key,2)[0] -> uniform key
    tf2x32(kk[0], kk[1], 0u, 1u, kB0, kB1); // split(key,2)[1] -> randint key
    U[0] = kA0; U[1] = kA1;
    tf2x32(kB0, kB1, 0u, 1u, t0, t1);       // randint lower-bits key
    P[0] = t0; P[1] = t1;
  };
  uint32_t U1[2],P1[2],U2[2],P2[2],U3[2],P3[2];
  derive(K1, U1, P1); derive(K2, U2, P2); derive(K3, U3, P3);

  hipMemsetAsync(d_ws, 0, 64, stream);      // zero the atomic-max slots

  k_prep<<<1, 256, 0, stream>>>(w, wq);
  k_maxp<<<KK, 256, 0, stream>>>(x, wq, scal + 1);
  if (bigws) {
    k_fi1cs<<<NOUT / TO, 256, 0, stream>>>(x, wq, scal, scal + 2, cws,
                                           U1[0], U1[1], P1[0], P1[1]);
    k_fi2split<<<3136, 256, 0, stream>>>(cws, scal, scal + 3, out,
                                         U2[0], U2[1], P2[0], P2[1]);
  } else {
    dim3 gC(49, 64);
    k_passC_nostore<<<gC, 64, 0, stream>>>(x, wq, scal, scal + 2,
                                           U1[0], U1[1], P1[0], P1[1]);
    dim3 gR(13, 64);
    k_passD_rec<<<gR, 256, 0, stream>>>(x, wq, scal, scal + 3, out,
                                        U1[0], U1[1], P1[0], P1[1],
                                        U2[0], U2[1], P2[0], P2[1]);
  }
  k_passE<<<NOUT / 256, 256, 0, stream>>>(out, scal,
                                          U3[0], U3[1], P3[0], P3[1]);
}